// Round 7
// baseline (127.706 us; speedup 1.0000x reference)
//
#include <hip/hip_runtime.h>
#include <hip/hip_bf16.h>

// Z[b,w,t] = sum_c Q[b,w,c] * (K[b,w+t,c] + bias[c,t])
// B=16, T=1024, C=128, K has 2T-1=2047 rows.
//
// Round 7: round-6 structure (one wave = one independent 32x32 tile, block
// 64x64, ONE barrier) but the diagonal gather goes through a PER-WAVE private
// LDS strip (bf16) instead of ds_bpermute:
//   - K band (128 rows) DMA-staged to LDS (32 KB)
//   - Q A-frags + bias B-frags from global (L2-hot), issued before the DMA;
//     bias MFMA runs before the barrier (overlaps staging latency)
//   - wave spills its 2 S tiles to its OWN strip (no barrier: within-wave DS
//     ordering), reads Z[i,j] = strip[i][i+j], adds bias acc, stores
//   - 48.5 KB LDS + launch_bounds(256,3) -> 3 blocks/CU (12 waves)

#define B_    16
#define T_    1024
#define C_    128
#define KT_   2047
#define SLD   66     // strip leading dim (bf16)

typedef unsigned short ushort_t;
typedef short bf16x8 __attribute__((ext_vector_type(8)));
typedef float f32x16 __attribute__((ext_vector_type(16)));

__device__ __forceinline__ unsigned short f2bf(float f) {
  unsigned int u = __float_as_uint(f);
  u += 0x7FFFu + ((u >> 16) & 1u);
  return (unsigned short)(u >> 16);
}
__device__ __forceinline__ float bf2f(unsigned short u) {
  return __uint_as_float(((unsigned int)u) << 16);
}

typedef const __attribute__((address_space(1))) unsigned int* gas_ptr;
typedef __attribute__((address_space(3))) unsigned int* las_ptr;
__device__ __forceinline__ void async_copy16(const void* g, void* l) {
  __builtin_amdgcn_global_load_lds((gas_ptr)g, (las_ptr)l, 16, 0, 0);
}

// swizzled fragment pointer: chunk kc (8 bf16) of LDS row `row` (rows 0..127)
__device__ __forceinline__ const bf16x8* frag(const ushort_t* t, int row, int kc) {
  return (const bf16x8*)(t + (((row << 4) + (kc ^ (row & 7))) << 3));
}

// ---------------- pre-pass: f32 -> bf16 (+ bias transpose) ----------------
#define QN4 524288    // 16*1024*128/4
#define KN4 1048064   // 16*2047*128/4
#define BN4 32768     // 128*1024/4

__global__ __launch_bounds__(256) void prepass(
    const float* __restrict__ Q, const float* __restrict__ K,
    const float* __restrict__ bias, ushort_t* __restrict__ Qb,
    ushort_t* __restrict__ Kb, ushort_t* __restrict__ bT) {
  int idx = blockIdx.x * 256 + threadIdx.x;
  if (idx < QN4) {
    float4 v = ((const float4*)Q)[idx];
    ((ushort4*)Qb)[idx] = make_ushort4(f2bf(v.x), f2bf(v.y), f2bf(v.z), f2bf(v.w));
  } else if (idx < QN4 + KN4) {
    int i = idx - QN4;
    float4 v = ((const float4*)K)[i];
    ((ushort4*)Kb)[i] = make_ushort4(f2bf(v.x), f2bf(v.y), f2bf(v.z), f2bf(v.w));
  } else if (idx < QN4 + KN4 + BN4) {
    int i = idx - (QN4 + KN4);
    int c = i >> 8;           // 0..127
    int g = i & 255;          // group of 4 along t
    float4 v = ((const float4*)(bias + c * T_))[g];
    int t = g << 2;
    bT[(t + 0) * C_ + c] = f2bf(v.x);
    bT[(t + 1) * C_ + c] = f2bf(v.y);
    bT[(t + 2) * C_ + c] = f2bf(v.z);
    bT[(t + 3) * C_ + c] = f2bf(v.w);
  }
}

// ---------------- main kernel ----------------
__global__ __launch_bounds__(256, 3) void swmm_main(
    const ushort_t* __restrict__ Qb, const ushort_t* __restrict__ Kb,
    const ushort_t* __restrict__ bT, float* __restrict__ out) {
  __shared__ __align__(16) ushort_t tile[128 * 128];   // 32 KB K band
  __shared__ __align__(4)  ushort_t strip[4][32 * SLD];// 16.5 KB per-wave S

  const int b    = blockIdx.z;
  const int w0   = blockIdx.y * 64;
  const int t0   = blockIdx.x * 64;
  const int g0   = w0 + t0;                  // band base row
  const int tid  = threadIdx.x;
  const int wv   = tid >> 6;
  const int lane = tid & 63;
  const int a    = wv >> 1;                  // row-half of block tile
  const int cc   = wv & 1;                   // col-half of block tile
  const int half = lane >> 5;
  const int l31  = lane & 31;

  const ushort_t* Kbase = Kb + (size_t)b * KT_ * C_;

  // ---- A frags (Q rows w0+32a+l31) + bias B frags from global, FIRST ----
  bf16x8 afrag[8], bfrag[8];
  {
    const ushort_t* arow = Qb + ((size_t)(b * T_ + w0 + (a << 5) + l31)) * C_;
    const ushort_t* brow = bT + (size_t)(t0 + (cc << 5) + l31) * C_;
#pragma unroll
    for (int s = 0; s < 8; ++s) {
      int kc = 2 * s + half;
      afrag[s] = *(const bf16x8*)(arow + (kc << 3));
      bfrag[s] = *(const bf16x8*)(brow + (kc << 3));
    }
  }

  // ---- stage K band rows [g0, g0+128) via DMA (after the frag loads) ----
  {
    const int p = lane & 15;
#pragma unroll
    for (int it = 0; it < 8; ++it) {
      int slot = it * 256 + tid;
      int r    = slot >> 4;                  // LDS row 0..127
      int c    = p ^ (r & 7);                // source chunk (XOR swizzle)
      int g    = g0 + r;
      if (g > KT_ - 1) g = KT_ - 1;          // rows past band end never gathered
      async_copy16(Kbase + (size_t)g * C_ + (c << 3),
                   &tile[(size_t)(slot - lane) * 8]);
    }
  }

  // ---- bias GEMM before the barrier (independent of LDS) ----
  f32x16 accB = {};
#pragma unroll
  for (int s = 0; s < 8; ++s)
    accB = __builtin_amdgcn_mfma_f32_32x32x16_bf16(afrag[s], bfrag[s], accB, 0, 0, 0);

  __syncthreads();   // K band resident

  // ---- S tiles: band cols base .. base+63, base = 32*(a+cc) ----
  const int base = (a + cc) << 5;
  f32x16 accS0 = {}, accS1 = {};
#pragma unroll
  for (int s = 0; s < 8; ++s) {
    int kc = 2 * s + half;
    accS0 = __builtin_amdgcn_mfma_f32_32x32x16_bf16(
        afrag[s], *frag(tile, base + l31, kc), accS0, 0, 0, 0);
  }
#pragma unroll
  for (int s = 0; s < 8; ++s) {
    int kc = 2 * s + half;
    accS1 = __builtin_amdgcn_mfma_f32_32x32x16_bf16(
        afrag[s], *frag(tile, base + 32 + l31, kc), accS1, 0, 0, 0);
  }

  // ---- spill S tiles to this wave's private strip (bf16) ----
  // C/D layout: col = lane&31, row i = (r&3) + 8*(r>>2) + 4*(lane>>5)
  ushort_t* Sw = strip[wv];
#pragma unroll
  for (int r = 0; r < 16; ++r) {
    const int i = (r & 3) + 8 * (r >> 2) + 4 * half;
    Sw[i * SLD + l31]      = f2bf(accS0[r]);
    Sw[i * SLD + 32 + l31] = f2bf(accS1[r]);
  }
  // no barrier: same wave writes and reads its own strip (in-order DS)

  // ---- gather diagonal + bias, store: Z[i,j] = S[i, i+j] + accB[i,j] ----
  float* orow = out + (size_t)(b * T_ + w0 + (a << 5)) * T_ + t0 + (cc << 5) + l31;
#pragma unroll
  for (int r = 0; r < 16; ++r) {
    const int i = (r & 3) + 8 * (r >> 2) + 4 * half;
    float sv = bf2f(Sw[i * SLD + i + l31]);   // j = l31, i+j <= 62
    orow[(size_t)i * T_] = sv + accB[r];
  }
}

// ---------------- fallback (round-1 style) if ws too small ----------------
#define LDB 136
#define KROWS 96
#define SS_LD 98
#define BWF   32
#define BTF   64
typedef float f32x4 __attribute__((ext_vector_type(4)));

__global__ __launch_bounds__(256) void swmm_fallback(
    const float* __restrict__ Q, const float* __restrict__ K,
    const float* __restrict__ bias, float* __restrict__ out) {
  __shared__ __align__(16) unsigned short Qs[BWF * LDB];
  __shared__ __align__(16) unsigned short Ks[KROWS * LDB];
  __shared__ __align__(16) unsigned short Bs[BTF * LDB];
  __shared__ __align__(16) float Ssf[BWF * SS_LD];

  const int b   = blockIdx.z;
  const int w0  = blockIdx.y * BWF;
  const int t0  = blockIdx.x * BTF;
  const int kbase = w0 + t0;
  const int tid = threadIdx.x;

  {
    const float4* src = (const float4*)(Q + (size_t)(b * T_ + w0) * C_);
    for (int v = tid; v < BWF * (C_ / 4); v += 256) {
      int r = v >> 5, cix = v & 31;
      float4 q = src[r * 32 + cix];
      unsigned short* d = &Qs[r * LDB + (cix << 2)];
      d[0] = f2bf(q.x); d[1] = f2bf(q.y); d[2] = f2bf(q.z); d[3] = f2bf(q.w);
    }
  }
  {
    for (int v = tid; v < KROWS * (C_ / 4); v += 256) {
      int r = v >> 5, cix = v & 31;
      int g = kbase + r;
      float4 kv = make_float4(0.f, 0.f, 0.f, 0.f);
      if (g < KT_) kv = ((const float4*)(K + ((size_t)b * KT_ + g) * C_))[cix];
      unsigned short* d = &Ks[r * LDB + (cix << 2)];
      d[0] = f2bf(kv.x); d[1] = f2bf(kv.y); d[2] = f2bf(kv.z); d[3] = f2bf(kv.w);
    }
  }
  {
    for (int v = tid; v < C_ * (BTF / 4); v += 256) {
      int c = v >> 4, jj = v & 15;
      float4 bv = ((const float4*)(bias + (size_t)c * T_ + t0))[jj];
      int j4 = jj << 2;
      Bs[(j4 + 0) * LDB + c] = f2bf(bv.x);
      Bs[(j4 + 1) * LDB + c] = f2bf(bv.y);
      Bs[(j4 + 2) * LDB + c] = f2bf(bv.z);
      Bs[(j4 + 3) * LDB + c] = f2bf(bv.w);
    }
  }
  __syncthreads();

  const int wv    = tid >> 6;
  const int lane  = tid & 63;
  const int frow  = lane & 15;
  const int koff  = (lane >> 4) * 8;
  const int drow4 = (lane >> 4) * 4;
  const int NS = KROWS / 16;

  for (int s = wv; s < 2 * NS; s += 4) {
    int mb = s / NS, nn = s % NS;
    int m0 = mb * 16, nn0 = nn * 16;
    const unsigned short* arow = &Qs[(m0 + frow) * LDB + koff];
    const unsigned short* brow = &Ks[(nn0 + frow) * LDB + koff];
    f32x4 acc = {0.f, 0.f, 0.f, 0.f};
#pragma unroll
    for (int k0 = 0; k0 < C_; k0 += 32) {
      bf16x8 aa = *(const bf16x8*)(arow + k0);
      bf16x8 bb = *(const bf16x8*)(brow + k0);
      acc = __builtin_amdgcn_mfma_f32_16x16x32_bf16(aa, bb, acc, 0, 0, 0);
    }
#pragma unroll
    for (int r = 0; r < 4; ++r)
      Ssf[(m0 + drow4 + r) * SS_LD + nn0 + frow] = acc[r];
  }

  f32x4 bacc[2];
#pragma unroll
  for (int q = 0; q < 2; ++q) {
    int idx = wv + q * 4;
    int m0 = (idx >> 2) * 16, j0 = (idx & 3) * 16;
    const unsigned short* arow = &Qs[(m0 + frow) * LDB + koff];
    const unsigned short* brow = &Bs[(j0 + frow) * LDB + koff];
    f32x4 acc = {0.f, 0.f, 0.f, 0.f};
#pragma unroll
    for (int k0 = 0; k0 < C_; k0 += 32) {
      bf16x8 aa = *(const bf16x8*)(arow + k0);
      bf16x8 bb = *(const bf16x8*)(brow + k0);
      acc = __builtin_amdgcn_mfma_f32_16x16x32_bf16(aa, bb, acc, 0, 0, 0);
    }
    bacc[q] = acc;
  }
  __syncthreads();

#pragma unroll
  for (int q = 0; q < 2; ++q) {
    int idx = wv + q * 4;
    int m0 = (idx >> 2) * 16, j0 = (idx & 3) * 16;
#pragma unroll
    for (int r = 0; r < 4; ++r) {
      int i = m0 + drow4 + r;
      int j = j0 + frow;
      out[(size_t)(b * T_ + w0 + i) * T_ + t0 + j] = bacc[q][r] + Ssf[i * SS_LD + i + j];
    }
  }
}

extern "C" void kernel_launch(void* const* d_in, const int* in_sizes, int n_in,
                              void* d_out, int out_size, void* d_ws, size_t ws_size,
                              hipStream_t stream) {
  const float* Q    = (const float*)d_in[0];
  const float* K    = (const float*)d_in[1];
  const float* bias = (const float*)d_in[2];
  float* out = (float*)d_out;

  const size_t QB = (size_t)B_ * T_ * C_ * 2;        // 4 MB
  const size_t KB = (size_t)B_ * KT_ * C_ * 2;       // 8.38 MB
  const size_t TB = (size_t)T_ * C_ * 2;             // 0.25 MB

  if (ws_size >= QB + KB + TB) {
    ushort_t* Qb = (ushort_t*)d_ws;
    ushort_t* Kb = (ushort_t*)((char*)d_ws + QB);
    ushort_t* bT = (ushort_t*)((char*)d_ws + QB + KB);
    prepass<<<(QN4 + KN4 + BN4) / 256, 256, 0, stream>>>(Q, K, bias, Qb, Kb, bT);
    swmm_main<<<dim3(16, 16, B_), dim3(256), 0, stream>>>(Qb, Kb, bT, out);
  } else {
    swmm_fallback<<<dim3(T_ / BTF, T_ / BWF, B_), dim3(256), 0, stream>>>(Q, K, bias, out);
  }
}